// Round 15
// baseline (170.788 us; speedup 1.0000x reference)
//
#include <hip/hip_runtime.h>
#include <hip/hip_bf16.h>

#define N_NODES 100000
#define N_EDGES 1600000
#define IN_DIM  256
#define OUT_DIM 128

#define TROWS   16                                 // rows per GEMM tile
#define NT      (N_NODES / TROWS)                  // 6250 tiles exact
#define TPB     8                                  // tiles per GEMM block
#define GEMM_BLOCKS ((NT + TPB - 1) / TPB)         // 782

#define NBUCK   196                                // ceil(100000 / 512)
#define BSHIFT  9                                  // 512 nodes per bucket
#define BCAP    10240                              // per-bucket capacity (mean 8192)
#define BSTRIDE 16                                 // bcur padding: 1 line per bucket
#define EPB     2048                               // edges per coarse block
#define BIN_BLOCKS ((N_EDGES + EPB - 1) / EPB)     // 782

typedef __attribute__((ext_vector_type(8))) short bf16x8;
typedef __attribute__((ext_vector_type(4))) float f32x4;

__device__ __forceinline__ ushort f2bf(float f) {
    union { float f; unsigned u; } v; v.f = f;
    unsigned r = v.u + 0x7FFF + ((v.u >> 16) & 1);   // RNE
    return (ushort)(r >> 16);
}
__device__ __forceinline__ float bflo(unsigned u) {
    union { unsigned u; float f; } v; v.u = u << 16; return v.f;
}
__device__ __forceinline__ float bfhi(unsigned u) {
    union { unsigned u; float f; } v; v.u = u & 0xFFFF0000u; return v.f;
}

// ---------------- Pack W[256,128] f32 -> bf16 fragment-major ---------------
__global__ __launch_bounds__(256) void pack_w(const float* __restrict__ W,
                                              ushort* __restrict__ Wp) {
    const int t = blockIdx.x * 256 + threadIdx.x;
    if (t >= 4096) return;
    const int kk = t >> 9, n = (t >> 6) & 7, l = t & 63;
    const int kbase = kk * 32 + (l >> 4) * 8;
    const int col   = n * 16 + (l & 15);
    ushort* o = Wp + (size_t)t * 8;
#pragma unroll
    for (int j = 0; j < 8; ++j)
        o[j] = f2bf(W[(size_t)(kbase + j) * OUT_DIM + col]);
}

// --- Fused: double-buffered multi-tile MFMA GEMM + sorted coarse binning ---
// GEMM blocks: 8 tiles of 16x128 each, reg-staged prefetch of tile t+1
// issued before compute of tile t (loads in flight across compute+epilogue).
__global__ __launch_bounds__(256, 6) void gemm_coarse(const float* __restrict__ X,
                                                      const bf16x8* __restrict__ Bp,
                                                      ushort* __restrict__ H,
                                                      const int* __restrict__ esrc,
                                                      const int* __restrict__ edst,
                                                      const float* __restrict__ eval,
                                                      int* __restrict__ bcur,
                                                      int2* __restrict__ binned) {
    __shared__ char smem[22784];                   // GEMM: 2x8KB bufs / coarse: 22.25KB

    const int tid  = threadIdx.x;
    const int lane = tid & 63;
    const int wv   = tid >> 6;

    if (blockIdx.x >= GEMM_BLOCKS) {
        // ---- coarse binning with in-LDS counting sort (2048-edge chunk) ----
        int*   cnt   = (int*)smem;                 // [196]
        int*   lbase = (int*)smem + 256;           // [196]
        int*   sbase = (int*)smem + 512;           // [196]
        int*   cur   = (int*)smem + 768;           // [196]
        int2*  lrec  = (int2*)(smem + 4096);       // [2048] 16 KB
        unsigned char* lbid = (unsigned char*)smem + 20480;  // [2048]

        const int blk = blockIdx.x - GEMM_BLOCKS;
        const int cb  = blk * EPB;
        const int lim = (N_EDGES - cb < EPB) ? (N_EDGES - cb) : EPB;

        if (tid < NBUCK) cnt[tid] = 0;
        __syncthreads();
        for (int i = tid; i < lim; i += 256)
            atomicAdd(&cnt[edst[cb + i] >> BSHIFT], 1);
        __syncthreads();

        // exclusive scan of cnt[0..195] -> lbase
        {
            __shared__ int wsum[4];
            const int v = (tid < NBUCK) ? cnt[tid] : 0;
            int sv = v;
#pragma unroll
            for (int d = 1; d < 64; d <<= 1) {
                const int t = __shfl_up(sv, d, 64);
                if (lane >= d) sv += t;
            }
            if (lane == 63) wsum[wv] = sv;
            __syncthreads();
            int wx = 0;
#pragma unroll
            for (int w = 0; w < 4; ++w) if (w < wv) wx += wsum[w];
            if (tid < NBUCK) {
                const int ex = wx + sv - v;
                lbase[tid] = ex;
                cur[tid]   = ex;
                sbase[tid] = v ? atomicAdd(&bcur[tid * BSTRIDE], v) : 0;
            }
        }
        __syncthreads();

        // scatter into LDS in bucket-sorted order
        for (int i = tid; i < lim; i += 256) {
            const int d = edst[cb + i];
            const int b = d >> BSHIFT;
            const int pos = atomicAdd(&cur[b], 1);
            int2 rec;
            rec.x = esrc[cb + i] | ((d & 511) << 20);
            rec.y = __float_as_int(eval[cb + i]);
            lrec[pos] = rec;
            lbid[pos] = (unsigned char)b;
        }
        __syncthreads();

        // write out sorted: consecutive i -> consecutive global positions
        for (int i = tid; i < lim; i += 256) {
            const int b   = lbid[i];
            const int off = sbase[b] + (i - lbase[b]);
            if (off < BCAP)
                binned[(size_t)b * BCAP + off] = lrec[i];
        }
        return;
    }

    // ---- GEMM: 8 tiles x (16 rows x 128 cols), double-buffered ----
    const int t0    = blockIdx.x * TPB;
    const int ntile = (NT - t0 < TPB) ? (NT - t0) : TPB;

    // staging coords: thread -> (row, 4 chunks of 4 floats)
    const int srow = tid >> 4;                     // 0..15
    const int sc0  = tid & 15;
    const int sxr  = (srow & 7) << 4;

    // compute coords
    const int wid  = wv;                           // col quarter 0..3
    const int rlo  = lane & 15;
    const int kseg = lane >> 4;
    const int rxor = (rlo & 7) << 4;

    float4 pre0, pre1, pre2, pre3;

#define ISSUE(tile) {                                                          \
        const float* gp = X + (size_t)((tile) * TROWS + srow) * IN_DIM;        \
        pre0 = *(const float4*)(gp + (sc0 +  0) * 4);                          \
        pre1 = *(const float4*)(gp + (sc0 + 16) * 4);                          \
        pre2 = *(const float4*)(gp + (sc0 + 32) * 4);                          \
        pre3 = *(const float4*)(gp + (sc0 + 48) * 4); }

#define CONVSTORE(base) {                                                      \
        ushort4 b4;                                                            \
        b4.x=f2bf(pre0.x); b4.y=f2bf(pre0.y); b4.z=f2bf(pre0.z); b4.w=f2bf(pre0.w); \
        *(ushort4*)((base) + ((srow*512 + (sc0+ 0)*8) ^ sxr)) = b4;            \
        b4.x=f2bf(pre1.x); b4.y=f2bf(pre1.y); b4.z=f2bf(pre1.z); b4.w=f2bf(pre1.w); \
        *(ushort4*)((base) + ((srow*512 + (sc0+16)*8) ^ sxr)) = b4;            \
        b4.x=f2bf(pre2.x); b4.y=f2bf(pre2.y); b4.z=f2bf(pre2.z); b4.w=f2bf(pre2.w); \
        *(ushort4*)((base) + ((srow*512 + (sc0+32)*8) ^ sxr)) = b4;            \
        b4.x=f2bf(pre3.x); b4.y=f2bf(pre3.y); b4.z=f2bf(pre3.z); b4.w=f2bf(pre3.w); \
        *(ushort4*)((base) + ((srow*512 + (sc0+48)*8) ^ sxr)) = b4; }

    ISSUE(t0);
    CONVSTORE(smem);
    int cur = 0;

    for (int tt = 0; tt < ntile; ++tt) {
        const bool pf = (tt + 1 < ntile);
        if (pf) ISSUE(t0 + tt + 1);                // loads in flight over compute

        __syncthreads();                           // buf[cur] ready

        const char* buf = smem + cur * 8192;
        f32x4 acc[2] = {};
#pragma unroll
        for (int kk = 0; kk < 8; ++kk) {
            const bf16x8 A = *(const bf16x8*)(buf + rlo * 512
                                              + ((kk * 64 + kseg * 16) ^ rxor));
            const bf16x8* bbase = Bp + (size_t)(kk * 8 + wid * 2) * 64 + lane;
            acc[0] = __builtin_amdgcn_mfma_f32_16x16x32_bf16(A, bbase[0],  acc[0], 0, 0, 0);
            acc[1] = __builtin_amdgcn_mfma_f32_16x16x32_bf16(A, bbase[64], acc[1], 0, 0, 0);
        }

        // epilogue: row = tile*16 + kseg*4 + r, col = wid*32 + n*16 + rlo
        const int grow0 = (t0 + tt) * TROWS + kseg * 4;
#pragma unroll
        for (int n = 0; n < 2; ++n)
#pragma unroll
            for (int r = 0; r < 4; ++r)
                H[(size_t)(grow0 + r) * OUT_DIM + wid * 32 + n * 16 + rlo]
                    = f2bf(acc[n][r]);

        __syncthreads();                           // all waves done reading buf[cur]
        if (pf) CONVSTORE(smem + (cur ^ 1) * 8192);
        cur ^= 1;
    }
#undef ISSUE
#undef CONVSTORE
}

// ---------------- Tiny scan: 196 bucket sizes -> exclusive bases -----------
__global__ __launch_bounds__(256) void scan_buckets(const int* __restrict__ bcur,
                                                    int* __restrict__ gbase) {
    __shared__ int ws[4];
    const int tid = threadIdx.x, lane = tid & 63, wid = tid >> 6;
    const int v = (tid < NBUCK) ? bcur[tid * BSTRIDE] : 0;
    int sv = v;
#pragma unroll
    for (int d = 1; d < 64; d <<= 1) {
        const int t = __shfl_up(sv, d, 64);
        if (lane >= d) sv += t;
    }
    if (lane == 63) ws[wid] = sv;
    __syncthreads();
    int wx = 0;
#pragma unroll
    for (int w = 0; w < 4; ++w) if (w < wid) wx += ws[w];
    if (tid < NBUCK) gbase[tid] = wx + sv - v;     // exclusive
}

// ------- Fine pass: per-bucket LDS node-hist + scan -> offsets + CSR -------
__global__ __launch_bounds__(1024) void bin_fine(const int* __restrict__ bcur,
                                                 const int* __restrict__ gbase,
                                                 const int2* __restrict__ binned,
                                                 int* __restrict__ offsets,
                                                 int2* __restrict__ recs) {
    __shared__ int nh[512];
    __shared__ int cur[512];
    __shared__ int ws[4];
    const int b   = blockIdx.x;
    const int tid = threadIdx.x, lane = tid & 63, wid = tid >> 6;
    const int node0 = b << BSHIFT;
    int nn = N_NODES - node0; if (nn > 512) nn = 512;
    int size = bcur[b * BSTRIDE]; if (size > BCAP) size = BCAP;
    const int2* in = binned + (size_t)b * BCAP;
    const int base_out = gbase[b];

    if (tid < 512) nh[tid] = 0;
    __syncthreads();
    for (int k = tid; k < size; k += 1024)
        atomicAdd(&nh[(in[k].x >> 20) & 511], 1);
    __syncthreads();

    // exclusive scan over nh[0..511]; threads 0..255 own pair (2t, 2t+1)
    int a0 = 0, ts = 0, sv = 0;
    if (tid < 256) {
        a0 = nh[2 * tid];
        const int a1 = nh[2 * tid + 1];
        ts = a0 + a1;
        sv = ts;
#pragma unroll
        for (int d = 1; d < 64; d <<= 1) {
            const int t = __shfl_up(sv, d, 64);
            if (lane >= d) sv += t;
        }
        if (lane == 63) ws[wid] = sv;
    }
    __syncthreads();
    if (tid < 256) {
        int wx = 0;
#pragma unroll
        for (int w = 0; w < 4; ++w) if (w < wid) wx += ws[w];
        const int ex = wx + sv - ts;               // exclusive prefix of pair
        cur[2 * tid]     = base_out + ex;
        cur[2 * tid + 1] = base_out + ex + a0;
        if (2 * tid < nn)     offsets[node0 + 2 * tid]     = base_out + ex;
        if (2 * tid + 1 < nn) offsets[node0 + 2 * tid + 1] = base_out + ex + a0;
    }
    if (b == 0 && tid == 0) offsets[N_NODES] = N_EDGES;
    __syncthreads();

    for (int k = tid; k < size; k += 1024) {
        const int2 r = in[k];
        const int pos = atomicAdd(&cur[(r.x >> 20) & 511], 1);
        int2 o; o.x = r.x & 0xFFFFF; o.y = r.y;
        recs[pos] = o;
    }
}

// ------- SpMM pull: 4 nodes/wave, 16 lanes/node, uint4 gathers, ReLU -------
__global__ __launch_bounds__(256) void spmm_pull(const ushort* __restrict__ H,
                                                 const int* __restrict__ offsets,
                                                 const int2* __restrict__ recs,
                                                 float* __restrict__ out) {
    const int tid   = threadIdx.x;
    const int lane  = tid & 63;
    const int g     = lane >> 4;                   // node group 0..3
    const int c     = lane & 15;                   // 16B col-chunk 0..15
    const int gwave = blockIdx.x * 4 + (tid >> 6);
    const int node  = gwave * 4 + g;
    if (node >= N_NODES) return;

    const int beg = offsets[node];
    const int end = offsets[node + 1];

    float a0 = 0.f, a1 = 0.f, a2 = 0.f, a3 = 0.f;
    float a4 = 0.f, a5 = 0.f, a6 = 0.f, a7 = 0.f;

    int e = beg;
    for (; e + 3 < end; e += 4) {                  // 4-edge unroll per group
        const int2 r0 = recs[e + 0];
        const int2 r1 = recs[e + 1];
        const int2 r2 = recs[e + 2];
        const int2 r3 = recs[e + 3];
        const uint4 h0 = *((const uint4*)(H + (size_t)r0.x * OUT_DIM) + c);
        const uint4 h1 = *((const uint4*)(H + (size_t)r1.x * OUT_DIM) + c);
        const uint4 h2 = *((const uint4*)(H + (size_t)r2.x * OUT_DIM) + c);
        const uint4 h3 = *((const uint4*)(H + (size_t)r3.x * OUT_DIM) + c);
        const float v0 = __int_as_float(r0.y), v1 = __int_as_float(r1.y);
        const float v2 = __int_as_float(r2.y), v3 = __int_as_float(r3.y);
        a0 = fmaf(v0, bflo(h0.x), a0);  a1 = fmaf(v0, bfhi(h0.x), a1);
        a2 = fmaf(v0, bflo(h0.y), a2);  a3 = fmaf(v0, bfhi(h0.y), a3);
        a4 = fmaf(v0, bflo(h0.z), a4);  a5 = fmaf(v0, bfhi(h0.z), a5);
        a6 = fmaf(v0, bflo(h0.w), a6);  a7 = fmaf(v0, bfhi(h0.w), a7);
        a0 = fmaf(v1, bflo(h1.x), a0);  a1 = fmaf(v1, bfhi(h1.x), a1);
        a2 = fmaf(v1, bflo(h1.y), a2);  a3 = fmaf(v1, bfhi(h1.y), a3);
        a4 = fmaf(v1, bflo(h1.z), a4);  a5 = fmaf(v1, bfhi(h1.z), a5);
        a6 = fmaf(v1, bflo(h1.w), a6);  a7 = fmaf(v1, bfhi(h1.w), a7);
        a0 = fmaf(v2, bflo(h2.x), a0);  a1 = fmaf(v2, bfhi(h2.x), a1);
        a2 = fmaf(v2, bflo(h2.y), a2);  a3 = fmaf(v2, bfhi(h2.y), a3);
        a4 = fmaf(v2, bflo(h2.z), a4);  a5 = fmaf(v2, bfhi(h2.z), a5);
        a6 = fmaf(v2, bflo(h2.w), a6);  a7 = fmaf(v2, bfhi(h2.w), a7);
        a0 = fmaf(v3, bflo(h3.x), a0);  a1 = fmaf(v3, bfhi(h3.x), a1);
        a2 = fmaf(v3, bflo(h3.y), a2);  a3 = fmaf(v3, bfhi(h3.y), a3);
        a4 = fmaf(v3, bflo(h3.z), a4);  a5 = fmaf(v3, bfhi(h3.z), a5);
        a6 = fmaf(v3, bflo(h3.w), a6);  a7 = fmaf(v3, bfhi(h3.w), a7);
    }
    for (; e < end; ++e) {
        const int2 r0 = recs[e];
        const float v0 = __int_as_float(r0.y);
        const uint4 h0 = *((const uint4*)(H + (size_t)r0.x * OUT_DIM) + c);
        a0 = fmaf(v0, bflo(h0.x), a0);  a1 = fmaf(v0, bfhi(h0.x), a1);
        a2 = fmaf(v0, bflo(h0.y), a2);  a3 = fmaf(v0, bfhi(h0.y), a3);
        a4 = fmaf(v0, bflo(h0.z), a4);  a5 = fmaf(v0, bfhi(h0.z), a5);
        a6 = fmaf(v0, bflo(h0.w), a6);  a7 = fmaf(v0, bfhi(h0.w), a7);
    }

    float* op = out + (size_t)node * OUT_DIM + c * 8;
    float4 o0, o1;
    o0.x = fmaxf(a0, 0.f); o0.y = fmaxf(a1, 0.f);
    o0.z = fmaxf(a2, 0.f); o0.w = fmaxf(a3, 0.f);
    o1.x = fmaxf(a4, 0.f); o1.y = fmaxf(a5, 0.f);
    o1.z = fmaxf(a6, 0.f); o1.w = fmaxf(a7, 0.f);
    *reinterpret_cast<float4*>(op)     = o0;
    *reinterpret_cast<float4*>(op + 4) = o1;
}

extern "C" void kernel_launch(void* const* d_in, const int* in_sizes, int n_in,
                              void* d_out, int out_size, void* d_ws, size_t ws_size,
                              hipStream_t stream) {
    const float* X    = (const float*)d_in[0];   // [N_NODES, IN_DIM]
    const float* W    = (const float*)d_in[1];   // [IN_DIM, OUT_DIM]
    const int*   esrc = (const int*)d_in[2];     // [N_EDGES]
    const int*   edst = (const int*)d_in[3];     // [N_EDGES]
    const float* eval = (const float*)d_in[4];   // [N_EDGES]
    float*       out  = (float*)d_out;           // [N_NODES, OUT_DIM]

    // Workspace layout (~55.4 MB)
    char* ws = (char*)d_ws;
    ushort* Hb     = (ushort*)ws;  ws += (size_t)N_NODES * OUT_DIM * sizeof(ushort);   // 25.6 MB
    ushort* Wp     = (ushort*)ws;  ws += (size_t)4096 * 8 * sizeof(ushort);            // 64 KB
    int*    offsets= (int*)ws;     ws += (((size_t)(N_NODES + 1) * 4 + 127) & ~(size_t)127);
    int*    bcur   = (int*)ws;     ws += (size_t)NBUCK * BSTRIDE * 4;                  // 12.5 KB padded
    int*    gbase  = (int*)ws;     ws += ((NBUCK * 4 + 127) & ~127);
    int2*   binned = (int2*)ws;    ws += (size_t)NBUCK * BCAP * sizeof(int2);          // 16.1 MB
    int2*   recs   = (int2*)ws;    // 12.8 MB

    // 1) Pack W; zero bucket cursors; fused [dbuf GEMM || sorted coarse bin]
    pack_w<<<16, 256, 0, stream>>>(W, Wp);
    hipMemsetAsync(bcur, 0, (size_t)NBUCK * BSTRIDE * 4, stream);
    gemm_coarse<<<GEMM_BLOCKS + BIN_BLOCKS, 256, 0, stream>>>(X, (const bf16x8*)Wp, Hb,
                                                              esrc, edst, eval,
                                                              bcur, binned);

    // 2) Bucket bases, per-bucket CSR finalize
    scan_buckets<<<1, 256, 0, stream>>>(bcur, gbase);
    bin_fine<<<NBUCK, 1024, 0, stream>>>(bcur, gbase, binned, offsets, recs);

    // 3) Pull-SpMM + ReLU: 4 nodes per wave, 16 lanes each
    spmm_pull<<<(N_NODES + 15) / 16, 256, 0, stream>>>(Hb, offsets, recs, out);
}

// Round 16
// 136.302 us; speedup vs baseline: 1.2530x; 1.2530x over previous
//
#include <hip/hip_runtime.h>
#include <hip/hip_bf16.h>

#define N_NODES 100000
#define N_EDGES 1600000
#define IN_DIM  256
#define OUT_DIM 128

#define GEMM_ROWS   32
#define GEMM_BLOCKS (N_NODES / GEMM_ROWS)          // 3125 exact

#define NBUCK   196                                // ceil(100000 / 512)
#define BSHIFT  9                                  // 512 nodes per bucket
#define BCAP    10240                              // per-bucket capacity (mean 8192)
#define BSTRIDE 16                                 // bcur padding: 1 line per bucket
#define EPB     2048                               // edges per coarse block
#define BIN_BLOCKS ((N_EDGES + EPB - 1) / EPB)     // 782

typedef __attribute__((ext_vector_type(8))) short bf16x8;
typedef __attribute__((ext_vector_type(4))) float f32x4;

__device__ __forceinline__ ushort f2bf(float f) {
    union { float f; unsigned u; } v; v.f = f;
    unsigned r = v.u + 0x7FFF + ((v.u >> 16) & 1);   // RNE
    return (ushort)(r >> 16);
}
__device__ __forceinline__ float bflo(unsigned u) {
    union { unsigned u; float f; } v; v.u = u << 16; return v.f;
}
__device__ __forceinline__ float bfhi(unsigned u) {
    union { unsigned u; float f; } v; v.u = u & 0xFFFF0000u; return v.f;
}

// ---------------- Pack W[256,128] f32 -> bf16 fragment-major ---------------
__global__ __launch_bounds__(256) void pack_w(const float* __restrict__ W,
                                              ushort* __restrict__ Wp) {
    const int t = blockIdx.x * 256 + threadIdx.x;
    if (t >= 4096) return;
    const int kk = t >> 9, n = (t >> 6) & 7, l = t & 63;
    const int kbase = kk * 32 + (l >> 4) * 8;
    const int col   = n * 16 + (l & 15);
    ushort* o = Wp + (size_t)t * 8;
#pragma unroll
    for (int j = 0; j < 8; ++j)
        o[j] = f2bf(W[(size_t)(kbase + j) * OUT_DIM + col]);
}

// --- Fused: 32-row LDS-staged MFMA GEMM (R14) + EPB-2048 sorted coarse (R13)
// Union LDS 22.6 KB -> 7 blocks/CU.
__global__ __launch_bounds__(256, 7) void gemm_coarse(const float* __restrict__ X,
                                                      const bf16x8* __restrict__ Bp,
                                                      ushort* __restrict__ H,
                                                      const int* __restrict__ esrc,
                                                      const int* __restrict__ edst,
                                                      const float* __restrict__ eval,
                                                      int* __restrict__ bcur,
                                                      int2* __restrict__ binned) {
    __shared__ char smem[22656];                   // GEMM 16.1KB / coarse 22.1KB

    const int tid  = threadIdx.x;
    const int lane = tid & 63;
    const int wv   = tid >> 6;

    if (blockIdx.x >= GEMM_BLOCKS) {
        // ---- coarse binning with in-LDS counting sort (2048-edge chunk) ----
        int*   cnt   = (int*)smem;                 // [196]
        int*   lbase = (int*)smem + 256;           // [196]
        int*   sbase = (int*)smem + 512;           // [196]
        int*   cur   = (int*)smem + 768;           // [196]
        int2*  lrec  = (int2*)(smem + 4096);       // [2048] 16 KB
        unsigned char* lbid = (unsigned char*)smem + 20480;  // [2048]

        const int blk = blockIdx.x - GEMM_BLOCKS;
        const int cb  = blk * EPB;
        const int lim = (N_EDGES - cb < EPB) ? (N_EDGES - cb) : EPB;

        if (tid < NBUCK) cnt[tid] = 0;
        __syncthreads();
        for (int i = tid; i < lim; i += 256)
            atomicAdd(&cnt[edst[cb + i] >> BSHIFT], 1);
        __syncthreads();

        // exclusive scan of cnt[0..195] -> lbase
        {
            __shared__ int wsum[4];
            const int v = (tid < NBUCK) ? cnt[tid] : 0;
            int sv = v;
#pragma unroll
            for (int d = 1; d < 64; d <<= 1) {
                const int t = __shfl_up(sv, d, 64);
                if (lane >= d) sv += t;
            }
            if (lane == 63) wsum[wv] = sv;
            __syncthreads();
            int wx = 0;
#pragma unroll
            for (int w = 0; w < 4; ++w) if (w < wv) wx += wsum[w];
            if (tid < NBUCK) {
                const int ex = wx + sv - v;
                lbase[tid] = ex;
                cur[tid]   = ex;
                sbase[tid] = v ? atomicAdd(&bcur[tid * BSTRIDE], v) : 0;
            }
        }
        __syncthreads();

        // scatter into LDS in bucket-sorted order
        for (int i = tid; i < lim; i += 256) {
            const int d = edst[cb + i];
            const int b = d >> BSHIFT;
            const int pos = atomicAdd(&cur[b], 1);
            int2 rec;
            rec.x = esrc[cb + i] | ((d & 511) << 20);
            rec.y = __float_as_int(eval[cb + i]);
            lrec[pos] = rec;
            lbid[pos] = (unsigned char)b;
        }
        __syncthreads();

        // write out sorted: consecutive i -> consecutive global positions
        for (int i = tid; i < lim; i += 256) {
            const int b   = lbid[i];
            const int off = sbase[b] + (i - lbase[b]);
            if (off < BCAP)
                binned[(size_t)b * BCAP + off] = lrec[i];
        }
        return;
    }

    // ---- GEMM: 32 rows x 128 cols; 4 waves each own 32 rows x 32 cols ----
    ushort* xt = (ushort*)smem;
    const int row0 = blockIdx.x * GEMM_ROWS;       // exact: no bounds checks

    // stage: 8 iters, 4 rows/iter, convert f32->bf16, swizzled LDS store
#pragma unroll 4
    for (int it = 0; it < 8; ++it) {
        const int tr = it * 4 + (tid >> 6);
        const int tc = (tid & 63) * 4;
        const float4 v = *reinterpret_cast<const float4*>(
            X + (size_t)(row0 + tr) * IN_DIM + tc);
        ushort4 b4;
        b4.x = f2bf(v.x); b4.y = f2bf(v.y); b4.z = f2bf(v.z); b4.w = f2bf(v.w);
        const int byte = (tr * 512 + tc * 2) ^ ((tr & 7) << 4);
        *reinterpret_cast<ushort4*>((char*)xt + byte) = b4;
    }
    __syncthreads();

    const int wid  = wv;                           // col quarter 0..3
    const int rlo  = lane & 15;
    const int kseg = lane >> 4;
    const int rl0  = rlo;                          // A-frag local rows
    const int rl1  = rlo + 16;
    const int rxor = (rlo & 7) << 4;

    f32x4 acc[2][2] = {};

    for (int kk = 0; kk < 8; ++kk) {
        const int cb2 = (kk * 64 + kseg * 16) ^ rxor;
        const bf16x8 A0 = *reinterpret_cast<const bf16x8*>((const char*)xt + rl0 * 512 + cb2);
        const bf16x8 A1 = *reinterpret_cast<const bf16x8*>((const char*)xt + rl1 * 512 + cb2);
        const bf16x8* bbase = Bp + (size_t)(kk * 8 + wid * 2) * 64 + lane;
#pragma unroll
        for (int n = 0; n < 2; ++n) {
            const bf16x8 Bf = bbase[(size_t)n * 64];
            acc[0][n] = __builtin_amdgcn_mfma_f32_16x16x32_bf16(A0, Bf, acc[0][n], 0, 0, 0);
            acc[1][n] = __builtin_amdgcn_mfma_f32_16x16x32_bf16(A1, Bf, acc[1][n], 0, 0, 0);
        }
    }

    // C/D layout: col = wid*32 + n*16 + rlo, row = i*16 + kseg*4 + r
#pragma unroll
    for (int i = 0; i < 2; ++i)
#pragma unroll
        for (int r = 0; r < 4; ++r)
#pragma unroll
            for (int n = 0; n < 2; ++n)
                H[(size_t)(row0 + i * 16 + kseg * 4 + r) * OUT_DIM
                  + wid * 32 + n * 16 + rlo] = f2bf(acc[i][n][r]);
}

// ---------------- Tiny scan: 196 bucket sizes -> exclusive bases -----------
__global__ __launch_bounds__(256) void scan_buckets(const int* __restrict__ bcur,
                                                    int* __restrict__ gbase) {
    __shared__ int ws[4];
    const int tid = threadIdx.x, lane = tid & 63, wid = tid >> 6;
    const int v = (tid < NBUCK) ? bcur[tid * BSTRIDE] : 0;
    int sv = v;
#pragma unroll
    for (int d = 1; d < 64; d <<= 1) {
        const int t = __shfl_up(sv, d, 64);
        if (lane >= d) sv += t;
    }
    if (lane == 63) ws[wid] = sv;
    __syncthreads();
    int wx = 0;
#pragma unroll
    for (int w = 0; w < 4; ++w) if (w < wid) wx += ws[w];
    if (tid < NBUCK) gbase[tid] = wx + sv - v;     // exclusive
}

// ------- Fine pass: per-bucket LDS node-hist + scan -> offsets + CSR -------
__global__ __launch_bounds__(1024) void bin_fine(const int* __restrict__ bcur,
                                                 const int* __restrict__ gbase,
                                                 const int2* __restrict__ binned,
                                                 int* __restrict__ offsets,
                                                 int2* __restrict__ recs) {
    __shared__ int nh[512];
    __shared__ int cur[512];
    __shared__ int ws[4];
    const int b   = blockIdx.x;
    const int tid = threadIdx.x, lane = tid & 63, wid = tid >> 6;
    const int node0 = b << BSHIFT;
    int nn = N_NODES - node0; if (nn > 512) nn = 512;
    int size = bcur[b * BSTRIDE]; if (size > BCAP) size = BCAP;
    const int2* in = binned + (size_t)b * BCAP;
    const int base_out = gbase[b];

    if (tid < 512) nh[tid] = 0;
    __syncthreads();
    for (int k = tid; k < size; k += 1024)
        atomicAdd(&nh[(in[k].x >> 20) & 511], 1);
    __syncthreads();

    // exclusive scan over nh[0..511]; threads 0..255 own pair (2t, 2t+1)
    int a0 = 0, ts = 0, sv = 0;
    if (tid < 256) {
        a0 = nh[2 * tid];
        const int a1 = nh[2 * tid + 1];
        ts = a0 + a1;
        sv = ts;
#pragma unroll
        for (int d = 1; d < 64; d <<= 1) {
            const int t = __shfl_up(sv, d, 64);
            if (lane >= d) sv += t;
        }
        if (lane == 63) ws[wid] = sv;
    }
    __syncthreads();
    if (tid < 256) {
        int wx = 0;
#pragma unroll
        for (int w = 0; w < 4; ++w) if (w < wid) wx += ws[w];
        const int ex = wx + sv - ts;               // exclusive prefix of pair
        cur[2 * tid]     = base_out + ex;
        cur[2 * tid + 1] = base_out + ex + a0;
        if (2 * tid < nn)     offsets[node0 + 2 * tid]     = base_out + ex;
        if (2 * tid + 1 < nn) offsets[node0 + 2 * tid + 1] = base_out + ex + a0;
    }
    if (b == 0 && tid == 0) offsets[N_NODES] = N_EDGES;
    __syncthreads();

    for (int k = tid; k < size; k += 1024) {
        const int2 r = in[k];
        const int pos = atomicAdd(&cur[(r.x >> 20) & 511], 1);
        int2 o; o.x = r.x & 0xFFFFF; o.y = r.y;
        recs[pos] = o;
    }
}

// ------- SpMM pull: 4 nodes/wave, 16 lanes/node, uint4 gathers, ReLU -------
__global__ __launch_bounds__(256) void spmm_pull(const ushort* __restrict__ H,
                                                 const int* __restrict__ offsets,
                                                 const int2* __restrict__ recs,
                                                 float* __restrict__ out) {
    const int tid   = threadIdx.x;
    const int lane  = tid & 63;
    const int g     = lane >> 4;                   // node group 0..3
    const int c     = lane & 15;                   // 16B col-chunk 0..15
    const int gwave = blockIdx.x * 4 + (tid >> 6);
    const int node  = gwave * 4 + g;
    if (node >= N_NODES) return;

    const int beg = offsets[node];
    const int end = offsets[node + 1];

    float a0 = 0.f, a1 = 0.f, a2 = 0.f, a3 = 0.f;
    float a4 = 0.f, a5 = 0.f, a6 = 0.f, a7 = 0.f;

    int e = beg;
    for (; e + 3 < end; e += 4) {                  // 4-edge unroll per group
        const int2 r0 = recs[e + 0];
        const int2 r1 = recs[e + 1];
        const int2 r2 = recs[e + 2];
        const int2 r3 = recs[e + 3];
        const uint4 h0 = *((const uint4*)(H + (size_t)r0.x * OUT_DIM) + c);
        const uint4 h1 = *((const uint4*)(H + (size_t)r1.x * OUT_DIM) + c);
        const uint4 h2 = *((const uint4*)(H + (size_t)r2.x * OUT_DIM) + c);
        const uint4 h3 = *((const uint4*)(H + (size_t)r3.x * OUT_DIM) + c);
        const float v0 = __int_as_float(r0.y), v1 = __int_as_float(r1.y);
        const float v2 = __int_as_float(r2.y), v3 = __int_as_float(r3.y);
        a0 = fmaf(v0, bflo(h0.x), a0);  a1 = fmaf(v0, bfhi(h0.x), a1);
        a2 = fmaf(v0, bflo(h0.y), a2);  a3 = fmaf(v0, bfhi(h0.y), a3);
        a4 = fmaf(v0, bflo(h0.z), a4);  a5 = fmaf(v0, bfhi(h0.z), a5);
        a6 = fmaf(v0, bflo(h0.w), a6);  a7 = fmaf(v0, bfhi(h0.w), a7);
        a0 = fmaf(v1, bflo(h1.x), a0);  a1 = fmaf(v1, bfhi(h1.x), a1);
        a2 = fmaf(v1, bflo(h1.y), a2);  a3 = fmaf(v1, bfhi(h1.y), a3);
        a4 = fmaf(v1, bflo(h1.z), a4);  a5 = fmaf(v1, bfhi(h1.z), a5);
        a6 = fmaf(v1, bflo(h1.w), a6);  a7 = fmaf(v1, bfhi(h1.w), a7);
        a0 = fmaf(v2, bflo(h2.x), a0);  a1 = fmaf(v2, bfhi(h2.x), a1);
        a2 = fmaf(v2, bflo(h2.y), a2);  a3 = fmaf(v2, bfhi(h2.y), a3);
        a4 = fmaf(v2, bflo(h2.z), a4);  a5 = fmaf(v2, bfhi(h2.z), a5);
        a6 = fmaf(v2, bflo(h2.w), a6);  a7 = fmaf(v2, bfhi(h2.w), a7);
        a0 = fmaf(v3, bflo(h3.x), a0);  a1 = fmaf(v3, bfhi(h3.x), a1);
        a2 = fmaf(v3, bflo(h3.y), a2);  a3 = fmaf(v3, bfhi(h3.y), a3);
        a4 = fmaf(v3, bflo(h3.z), a4);  a5 = fmaf(v3, bfhi(h3.z), a5);
        a6 = fmaf(v3, bflo(h3.w), a6);  a7 = fmaf(v3, bfhi(h3.w), a7);
    }
    for (; e < end; ++e) {
        const int2 r0 = recs[e];
        const float v0 = __int_as_float(r0.y);
        const uint4 h0 = *((const uint4*)(H + (size_t)r0.x * OUT_DIM) + c);
        a0 = fmaf(v0, bflo(h0.x), a0);  a1 = fmaf(v0, bfhi(h0.x), a1);
        a2 = fmaf(v0, bflo(h0.y), a2);  a3 = fmaf(v0, bfhi(h0.y), a3);
        a4 = fmaf(v0, bflo(h0.z), a4);  a5 = fmaf(v0, bfhi(h0.z), a5);
        a6 = fmaf(v0, bflo(h0.w), a6);  a7 = fmaf(v0, bfhi(h0.w), a7);
    }

    float* op = out + (size_t)node * OUT_DIM + c * 8;
    float4 o0, o1;
    o0.x = fmaxf(a0, 0.f); o0.y = fmaxf(a1, 0.f);
    o0.z = fmaxf(a2, 0.f); o0.w = fmaxf(a3, 0.f);
    o1.x = fmaxf(a4, 0.f); o1.y = fmaxf(a5, 0.f);
    o1.z = fmaxf(a6, 0.f); o1.w = fmaxf(a7, 0.f);
    *reinterpret_cast<float4*>(op)     = o0;
    *reinterpret_cast<float4*>(op + 4) = o1;
}

extern "C" void kernel_launch(void* const* d_in, const int* in_sizes, int n_in,
                              void* d_out, int out_size, void* d_ws, size_t ws_size,
                              hipStream_t stream) {
    const float* X    = (const float*)d_in[0];   // [N_NODES, IN_DIM]
    const float* W    = (const float*)d_in[1];   // [IN_DIM, OUT_DIM]
    const int*   esrc = (const int*)d_in[2];     // [N_EDGES]
    const int*   edst = (const int*)d_in[3];     // [N_EDGES]
    const float* eval = (const float*)d_in[4];   // [N_EDGES]
    float*       out  = (float*)d_out;           // [N_NODES, OUT_DIM]

    // Workspace layout (~55.4 MB)
    char* ws = (char*)d_ws;
    ushort* Hb     = (ushort*)ws;  ws += (size_t)N_NODES * OUT_DIM * sizeof(ushort);   // 25.6 MB
    ushort* Wp     = (ushort*)ws;  ws += (size_t)4096 * 8 * sizeof(ushort);            // 64 KB
    int*    offsets= (int*)ws;     ws += (((size_t)(N_NODES + 1) * 4 + 127) & ~(size_t)127);
    int*    bcur   = (int*)ws;     ws += (size_t)NBUCK * BSTRIDE * 4;                  // 12.5 KB padded
    int*    gbase  = (int*)ws;     ws += ((NBUCK * 4 + 127) & ~127);
    int2*   binned = (int2*)ws;    ws += (size_t)NBUCK * BCAP * sizeof(int2);          // 16.1 MB
    int2*   recs   = (int2*)ws;    // 12.8 MB

    // 1) Pack W; zero bucket cursors; fused [GEMM || sorted coarse binning]
    pack_w<<<16, 256, 0, stream>>>(W, Wp);
    hipMemsetAsync(bcur, 0, (size_t)NBUCK * BSTRIDE * 4, stream);
    gemm_coarse<<<GEMM_BLOCKS + BIN_BLOCKS, 256, 0, stream>>>(X, (const bf16x8*)Wp, Hb,
                                                              esrc, edst, eval,
                                                              bcur, binned);

    // 2) Bucket bases, per-bucket CSR finalize
    scan_buckets<<<1, 256, 0, stream>>>(bcur, gbase);
    bin_fine<<<NBUCK, 1024, 0, stream>>>(bcur, gbase, binned, offsets, recs);

    // 3) Pull-SpMM + ReLU: 4 nodes per wave, 16 lanes each
    spmm_pull<<<(N_NODES + 15) / 16, 256, 0, stream>>>(Hb, offsets, recs, out);
}

// Round 17
// 127.098 us; speedup vs baseline: 1.3437x; 1.0724x over previous
//
#include <hip/hip_runtime.h>
#include <hip/hip_bf16.h>

#define N_NODES 100000
#define N_EDGES 1600000
#define IN_DIM  256
#define OUT_DIM 128

#define GEMM_ROWS   32
#define GEMM_BLOCKS (N_NODES / GEMM_ROWS)          // 3125 exact

#define NBUCK   196                                // ceil(100000 / 512)
#define BSHIFT  9                                  // 512 nodes per bucket
#define BCAP    10240                              // per-bucket capacity (mean 8192)
#define BSTRIDE 16                                 // bcur padding: 1 line per bucket
#define EPB     2048                               // edges per coarse block
#define BIN_BLOCKS ((N_EDGES + EPB - 1) / EPB)     // 782
#define TOTAL_BLOCKS (GEMM_BLOCKS + BIN_BLOCKS)    // 3907

typedef __attribute__((ext_vector_type(8))) short bf16x8;
typedef __attribute__((ext_vector_type(4))) float f32x4;

__device__ __forceinline__ ushort f2bf(float f) {
    union { float f; unsigned u; } v; v.f = f;
    unsigned r = v.u + 0x7FFF + ((v.u >> 16) & 1);   // RNE
    return (ushort)(r >> 16);
}
__device__ __forceinline__ float bflo(unsigned u) {
    union { unsigned u; float f; } v; v.u = u << 16; return v.f;
}
__device__ __forceinline__ float bfhi(unsigned u) {
    union { unsigned u; float f; } v; v.u = u & 0xFFFF0000u; return v.f;
}

// ---------------- Pack W[256,128] f32 -> bf16 fragment-major ---------------
__global__ __launch_bounds__(256) void pack_w(const float* __restrict__ W,
                                              ushort* __restrict__ Wp) {
    const int t = blockIdx.x * 256 + threadIdx.x;
    if (t >= 4096) return;
    const int kk = t >> 9, n = (t >> 6) & 7, l = t & 63;
    const int kbase = kk * 32 + (l >> 4) * 8;
    const int col   = n * 16 + (l & 15);
    ushort* o = Wp + (size_t)t * 8;
#pragma unroll
    for (int j = 0; j < 8; ++j)
        o[j] = f2bf(W[(size_t)(kbase + j) * OUT_DIM + col]);
}

// --- Fused (4:1 INTERLEAVED): 32-row MFMA GEMM + EPB-2048 sorted coarse ----
// Coarse blocks are spread through the grid (bid%5==4) so they co-execute
// with GEMM blocks instead of forming a serial tail.
__global__ __launch_bounds__(256, 7) void gemm_coarse(const float* __restrict__ X,
                                                      const bf16x8* __restrict__ Bp,
                                                      ushort* __restrict__ H,
                                                      const int* __restrict__ esrc,
                                                      const int* __restrict__ edst,
                                                      const float* __restrict__ eval,
                                                      int* __restrict__ bcur,
                                                      int2* __restrict__ binned) {
    __shared__ char smem[22656];                   // GEMM 16.1KB / coarse 22.1KB

    const int tid  = threadIdx.x;
    const int lane = tid & 63;
    const int wv   = tid >> 6;
    const int bid  = blockIdx.x;

    const bool is_coarse = ((bid % 5) == 4) || (bid == TOTAL_BLOCKS - 1);

    if (is_coarse) {
        // ---- coarse binning with in-LDS counting sort (2048-edge chunk) ----
        const int blk = (bid == TOTAL_BLOCKS - 1) ? (BIN_BLOCKS - 1) : (bid / 5);
        int*   cnt   = (int*)smem;                 // [196]
        int*   lbase = (int*)smem + 256;           // [196]
        int*   sbase = (int*)smem + 512;           // [196]
        int*   cur   = (int*)smem + 768;           // [196]
        int2*  lrec  = (int2*)(smem + 4096);       // [2048] 16 KB
        unsigned char* lbid = (unsigned char*)smem + 20480;  // [2048]

        const int cb  = blk * EPB;
        const int lim = (N_EDGES - cb < EPB) ? (N_EDGES - cb) : EPB;

        if (tid < NBUCK) cnt[tid] = 0;
        __syncthreads();
        for (int i = tid; i < lim; i += 256)
            atomicAdd(&cnt[edst[cb + i] >> BSHIFT], 1);
        __syncthreads();

        // exclusive scan of cnt[0..195] -> lbase
        {
            __shared__ int wsum[4];
            const int v = (tid < NBUCK) ? cnt[tid] : 0;
            int sv = v;
#pragma unroll
            for (int d = 1; d < 64; d <<= 1) {
                const int t = __shfl_up(sv, d, 64);
                if (lane >= d) sv += t;
            }
            if (lane == 63) wsum[wv] = sv;
            __syncthreads();
            int wx = 0;
#pragma unroll
            for (int w = 0; w < 4; ++w) if (w < wv) wx += wsum[w];
            if (tid < NBUCK) {
                const int ex = wx + sv - v;
                lbase[tid] = ex;
                cur[tid]   = ex;
                sbase[tid] = v ? atomicAdd(&bcur[tid * BSTRIDE], v) : 0;
            }
        }
        __syncthreads();

        // scatter into LDS in bucket-sorted order
        for (int i = tid; i < lim; i += 256) {
            const int d = edst[cb + i];
            const int b = d >> BSHIFT;
            const int pos = atomicAdd(&cur[b], 1);
            int2 rec;
            rec.x = esrc[cb + i] | ((d & 511) << 20);
            rec.y = __float_as_int(eval[cb + i]);
            lrec[pos] = rec;
            lbid[pos] = (unsigned char)b;
        }
        __syncthreads();

        // write out sorted: consecutive i -> consecutive global positions
        for (int i = tid; i < lim; i += 256) {
            const int b   = lbid[i];
            const int off = sbase[b] + (i - lbase[b]);
            if (off < BCAP)
                binned[(size_t)b * BCAP + off] = lrec[i];
        }
        return;
    }

    // ---- GEMM: 32 rows x 128 cols; 4 waves each own 32 rows x 32 cols ----
    const int gidx = bid - bid / 5;                // de-interleaved GEMM index
    ushort* xt = (ushort*)smem;
    const int row0 = gidx * GEMM_ROWS;             // exact: no bounds checks

    // stage: 8 iters, 4 rows/iter, convert f32->bf16, swizzled LDS store
#pragma unroll 4
    for (int it = 0; it < 8; ++it) {
        const int tr = it * 4 + (tid >> 6);
        const int tc = (tid & 63) * 4;
        const float4 v = *reinterpret_cast<const float4*>(
            X + (size_t)(row0 + tr) * IN_DIM + tc);
        ushort4 b4;
        b4.x = f2bf(v.x); b4.y = f2bf(v.y); b4.z = f2bf(v.z); b4.w = f2bf(v.w);
        const int byte = (tr * 512 + tc * 2) ^ ((tr & 7) << 4);
        *reinterpret_cast<ushort4*>((char*)xt + byte) = b4;
    }
    __syncthreads();

    const int wid  = wv;                           // col quarter 0..3
    const int rlo  = lane & 15;
    const int kseg = lane >> 4;
    const int rl0  = rlo;                          // A-frag local rows
    const int rl1  = rlo + 16;
    const int rxor = (rlo & 7) << 4;

    f32x4 acc[2][2] = {};

    for (int kk = 0; kk < 8; ++kk) {
        const int cb2 = (kk * 64 + kseg * 16) ^ rxor;
        const bf16x8 A0 = *reinterpret_cast<const bf16x8*>((const char*)xt + rl0 * 512 + cb2);
        const bf16x8 A1 = *reinterpret_cast<const bf16x8*>((const char*)xt + rl1 * 512 + cb2);
        const bf16x8* bbase = Bp + (size_t)(kk * 8 + wid * 2) * 64 + lane;
#pragma unroll
        for (int n = 0; n < 2; ++n) {
            const bf16x8 Bf = bbase[(size_t)n * 64];
            acc[0][n] = __builtin_amdgcn_mfma_f32_16x16x32_bf16(A0, Bf, acc[0][n], 0, 0, 0);
            acc[1][n] = __builtin_amdgcn_mfma_f32_16x16x32_bf16(A1, Bf, acc[1][n], 0, 0, 0);
        }
    }

    // C/D layout: col = wid*32 + n*16 + rlo, row = i*16 + kseg*4 + r
#pragma unroll
    for (int i = 0; i < 2; ++i)
#pragma unroll
        for (int r = 0; r < 4; ++r)
#pragma unroll
            for (int n = 0; n < 2; ++n)
                H[(size_t)(row0 + i * 16 + kseg * 4 + r) * OUT_DIM
                  + wid * 32 + n * 16 + rlo] = f2bf(acc[i][n][r]);
}

// ------- Fine pass (scan folded in): per-bucket node-hist -> offsets + CSR -
__global__ __launch_bounds__(1024) void bin_fine(const int* __restrict__ bcur,
                                                 const int2* __restrict__ binned,
                                                 int* __restrict__ offsets,
                                                 int2* __restrict__ recs) {
    __shared__ int nh[512];
    __shared__ int cur[512];
    __shared__ int ws[4];
    __shared__ int wsB[4];
    __shared__ int base_out_s;
    const int b   = blockIdx.x;
    const int tid = threadIdx.x, lane = tid & 63, wid = tid >> 6;
    const int node0 = b << BSHIFT;
    int nn = N_NODES - node0; if (nn > 512) nn = 512;
    int size = bcur[b * BSTRIDE]; if (size > BCAP) size = BCAP;
    const int2* in = binned + (size_t)b * BCAP;

    // per-block exclusive prefix over the 196 bucket sizes (replaces scan k.)
    if (tid < 256) {
        const int v = (tid < NBUCK) ? bcur[tid * BSTRIDE] : 0;
        int sv = v;
#pragma unroll
        for (int d = 1; d < 64; d <<= 1) {
            const int t = __shfl_up(sv, d, 64);
            if (lane >= d) sv += t;
        }
        if (lane == 63) wsB[wid] = sv;
        __syncthreads();
        int wx = 0;
#pragma unroll
        for (int w = 0; w < 4; ++w) if (w < wid) wx += wsB[w];
        if (tid == b) base_out_s = wx + sv - v;    // exclusive prefix at b
    } else {
        __syncthreads();
    }

    if (tid < 512) nh[tid] = 0;
    __syncthreads();
    const int base_out = base_out_s;
    for (int k = tid; k < size; k += 1024)
        atomicAdd(&nh[(in[k].x >> 20) & 511], 1);
    __syncthreads();

    // exclusive scan over nh[0..511]; threads 0..255 own pair (2t, 2t+1)
    int a0 = 0, ts = 0, sv = 0;
    if (tid < 256) {
        a0 = nh[2 * tid];
        const int a1 = nh[2 * tid + 1];
        ts = a0 + a1;
        sv = ts;
#pragma unroll
        for (int d = 1; d < 64; d <<= 1) {
            const int t = __shfl_up(sv, d, 64);
            if (lane >= d) sv += t;
        }
        if (lane == 63) ws[wid] = sv;
    }
    __syncthreads();
    if (tid < 256) {
        int wx = 0;
#pragma unroll
        for (int w = 0; w < 4; ++w) if (w < wid) wx += ws[w];
        const int ex = wx + sv - ts;               // exclusive prefix of pair
        cur[2 * tid]     = base_out + ex;
        cur[2 * tid + 1] = base_out + ex + a0;
        if (2 * tid < nn)     offsets[node0 + 2 * tid]     = base_out + ex;
        if (2 * tid + 1 < nn) offsets[node0 + 2 * tid + 1] = base_out + ex + a0;
    }
    if (b == 0 && tid == 0) offsets[N_NODES] = N_EDGES;
    __syncthreads();

    for (int k = tid; k < size; k += 1024) {
        const int2 r = in[k];
        const int pos = atomicAdd(&cur[(r.x >> 20) & 511], 1);
        int2 o; o.x = r.x & 0xFFFFF; o.y = r.y;
        recs[pos] = o;
    }
}

// ------- SpMM pull: 4 nodes/wave, 16 lanes/node, uint4 gathers, ReLU -------
__global__ __launch_bounds__(256) void spmm_pull(const ushort* __restrict__ H,
                                                 const int* __restrict__ offsets,
                                                 const int2* __restrict__ recs,
                                                 float* __restrict__ out) {
    const int tid   = threadIdx.x;
    const int lane  = tid & 63;
    const int g     = lane >> 4;                   // node group 0..3
    const int c     = lane & 15;                   // 16B col-chunk 0..15
    const int gwave = blockIdx.x * 4 + (tid >> 6);
    const int node  = gwave * 4 + g;
    if (node >= N_NODES) return;

    const int beg = offsets[node];
    const int end = offsets[node + 1];

    float a0 = 0.f, a1 = 0.f, a2 = 0.f, a3 = 0.f;
    float a4 = 0.f, a5 = 0.f, a6 = 0.f, a7 = 0.f;

    int e = beg;
    for (; e + 3 < end; e += 4) {                  // 4-edge unroll per group
        const int2 r0 = recs[e + 0];
        const int2 r1 = recs[e + 1];
        const int2 r2 = recs[e + 2];
        const int2 r3 = recs[e + 3];
        const uint4 h0 = *((const uint4*)(H + (size_t)r0.x * OUT_DIM) + c);
        const uint4 h1 = *((const uint4*)(H + (size_t)r1.x * OUT_DIM) + c);
        const uint4 h2 = *((const uint4*)(H + (size_t)r2.x * OUT_DIM) + c);
        const uint4 h3 = *((const uint4*)(H + (size_t)r3.x * OUT_DIM) + c);
        const float v0 = __int_as_float(r0.y), v1 = __int_as_float(r1.y);
        const float v2 = __int_as_float(r2.y), v3 = __int_as_float(r3.y);
        a0 = fmaf(v0, bflo(h0.x), a0);  a1 = fmaf(v0, bfhi(h0.x), a1);
        a2 = fmaf(v0, bflo(h0.y), a2);  a3 = fmaf(v0, bfhi(h0.y), a3);
        a4 = fmaf(v0, bflo(h0.z), a4);  a5 = fmaf(v0, bfhi(h0.z), a5);
        a6 = fmaf(v0, bflo(h0.w), a6);  a7 = fmaf(v0, bfhi(h0.w), a7);
        a0 = fmaf(v1, bflo(h1.x), a0);  a1 = fmaf(v1, bfhi(h1.x), a1);
        a2 = fmaf(v1, bflo(h1.y), a2);  a3 = fmaf(v1, bfhi(h1.y), a3);
        a4 = fmaf(v1, bflo(h1.z), a4);  a5 = fmaf(v1, bfhi(h1.z), a5);
        a6 = fmaf(v1, bflo(h1.w), a6);  a7 = fmaf(v1, bfhi(h1.w), a7);
        a0 = fmaf(v2, bflo(h2.x), a0);  a1 = fmaf(v2, bfhi(h2.x), a1);
        a2 = fmaf(v2, bflo(h2.y), a2);  a3 = fmaf(v2, bfhi(h2.y), a3);
        a4 = fmaf(v2, bflo(h2.z), a4);  a5 = fmaf(v2, bfhi(h2.z), a5);
        a6 = fmaf(v2, bflo(h2.w), a6);  a7 = fmaf(v2, bfhi(h2.w), a7);
        a0 = fmaf(v3, bflo(h3.x), a0);  a1 = fmaf(v3, bfhi(h3.x), a1);
        a2 = fmaf(v3, bflo(h3.y), a2);  a3 = fmaf(v3, bfhi(h3.y), a3);
        a4 = fmaf(v3, bflo(h3.z), a4);  a5 = fmaf(v3, bfhi(h3.z), a5);
        a6 = fmaf(v3, bflo(h3.w), a6);  a7 = fmaf(v3, bfhi(h3.w), a7);
    }
    for (; e < end; ++e) {
        const int2 r0 = recs[e];
        const float v0 = __int_as_float(r0.y);
        const uint4 h0 = *((const uint4*)(H + (size_t)r0.x * OUT_DIM) + c);
        a0 = fmaf(v0, bflo(h0.x), a0);  a1 = fmaf(v0, bfhi(h0.x), a1);
        a2 = fmaf(v0, bflo(h0.y), a2);  a3 = fmaf(v0, bfhi(h0.y), a3);
        a4 = fmaf(v0, bflo(h0.z), a4);  a5 = fmaf(v0, bfhi(h0.z), a5);
        a6 = fmaf(v0, bflo(h0.w), a6);  a7 = fmaf(v0, bfhi(h0.w), a7);
    }

    float* op = out + (size_t)node * OUT_DIM + c * 8;
    float4 o0, o1;
    o0.x = fmaxf(a0, 0.f); o0.y = fmaxf(a1, 0.f);
    o0.z = fmaxf(a2, 0.f); o0.w = fmaxf(a3, 0.f);
    o1.x = fmaxf(a4, 0.f); o1.y = fmaxf(a5, 0.f);
    o1.z = fmaxf(a6, 0.f); o1.w = fmaxf(a7, 0.f);
    *reinterpret_cast<float4*>(op)     = o0;
    *reinterpret_cast<float4*>(op + 4) = o1;
}

extern "C" void kernel_launch(void* const* d_in, const int* in_sizes, int n_in,
                              void* d_out, int out_size, void* d_ws, size_t ws_size,
                              hipStream_t stream) {
    const float* X    = (const float*)d_in[0];   // [N_NODES, IN_DIM]
    const float* W    = (const float*)d_in[1];   // [IN_DIM, OUT_DIM]
    const int*   esrc = (const int*)d_in[2];     // [N_EDGES]
    const int*   edst = (const int*)d_in[3];     // [N_EDGES]
    const float* eval = (const float*)d_in[4];   // [N_EDGES]
    float*       out  = (float*)d_out;           // [N_NODES, OUT_DIM]

    // Workspace layout (~55.4 MB)
    char* ws = (char*)d_ws;
    ushort* Hb     = (ushort*)ws;  ws += (size_t)N_NODES * OUT_DIM * sizeof(ushort);   // 25.6 MB
    ushort* Wp     = (ushort*)ws;  ws += (size_t)4096 * 8 * sizeof(ushort);            // 64 KB
    int*    offsets= (int*)ws;     ws += (((size_t)(N_NODES + 1) * 4 + 127) & ~(size_t)127);
    int*    bcur   = (int*)ws;     ws += (size_t)NBUCK * BSTRIDE * 4;                  // 12.5 KB padded
    int2*   binned = (int2*)ws;    ws += (size_t)NBUCK * BCAP * sizeof(int2);          // 16.1 MB
    int2*   recs   = (int2*)ws;    // 12.8 MB

    // 1) Pack W; zero bucket cursors; interleaved [GEMM || sorted coarse bin]
    pack_w<<<16, 256, 0, stream>>>(W, Wp);
    hipMemsetAsync(bcur, 0, (size_t)NBUCK * BSTRIDE * 4, stream);
    gemm_coarse<<<TOTAL_BLOCKS, 256, 0, stream>>>(X, (const bf16x8*)Wp, Hb,
                                                  esrc, edst, eval, bcur, binned);

    // 2) Per-bucket CSR finalize (bucket-base scan folded in)
    bin_fine<<<NBUCK, 1024, 0, stream>>>(bcur, binned, offsets, recs);

    // 3) Pull-SpMM + ReLU: 4 nodes per wave, 16 lanes each
    spmm_pull<<<(N_NODES + 15) / 16, 256, 0, stream>>>(Hb, offsets, recs, out);
}

// Round 18
// 122.979 us; speedup vs baseline: 1.3887x; 1.0335x over previous
//
#include <hip/hip_runtime.h>
#include <hip/hip_bf16.h>

#define N_NODES 100000
#define N_EDGES 1600000
#define IN_DIM  256
#define OUT_DIM 128

#define GEMM_ROWS   32
#define GEMM_BLOCKS (N_NODES / GEMM_ROWS)          // 3125 exact

#define NBUCK   196                                // ceil(100000 / 512)
#define BSHIFT  9                                  // 512 nodes per bucket
#define BCAP    10240                              // per-bucket capacity (mean 8192)
#define BSTRIDE 16                                 // bcur padding: 1 line per bucket
#define EPB     2048                               // edges per coarse block
#define BIN_BLOCKS ((N_EDGES + EPB - 1) / EPB)     // 782
#define TOTAL_BLOCKS (GEMM_BLOCKS + BIN_BLOCKS)    // 3907

typedef __attribute__((ext_vector_type(8))) short bf16x8;
typedef __attribute__((ext_vector_type(4))) float f32x4;

__device__ __forceinline__ ushort f2bf(float f) {
    union { float f; unsigned u; } v; v.f = f;
    unsigned r = v.u + 0x7FFF + ((v.u >> 16) & 1);   // RNE
    return (ushort)(r >> 16);
}
__device__ __forceinline__ float bflo(unsigned u) {
    union { unsigned u; float f; } v; v.u = u << 16; return v.f;
}
__device__ __forceinline__ float bfhi(unsigned u) {
    union { unsigned u; float f; } v; v.u = u & 0xFFFF0000u; return v.f;
}

// ------- Pack W[256,128] f32 -> bf16 fragment-major (+ zero bcur) ----------
__global__ __launch_bounds__(256) void pack_w(const float* __restrict__ W,
                                              ushort* __restrict__ Wp,
                                              int* __restrict__ bcur) {
    const int t = blockIdx.x * 256 + threadIdx.x;
    if (blockIdx.x == 0) {                         // fold: zero bucket cursors
        for (int i = threadIdx.x; i < NBUCK * BSTRIDE; i += 256) bcur[i] = 0;
    }
    if (t >= 4096) return;
    const int kk = t >> 9, n = (t >> 6) & 7, l = t & 63;
    const int kbase = kk * 32 + (l >> 4) * 8;
    const int col   = n * 16 + (l & 15);
    ushort* o = Wp + (size_t)t * 8;
#pragma unroll
    for (int j = 0; j < 8; ++j)
        o[j] = f2bf(W[(size_t)(kbase + j) * OUT_DIM + col]);
}

// --- Fused (4:1 INTERLEAVED): 32-row MFMA GEMM (B-frags preloaded to regs) -
// --- + EPB-2048 sorted coarse binning. launch_bounds(256,5): 102 VGPRs. ----
__global__ __launch_bounds__(256, 5) void gemm_coarse(const float* __restrict__ X,
                                                      const bf16x8* __restrict__ Bp,
                                                      ushort* __restrict__ H,
                                                      const int* __restrict__ esrc,
                                                      const int* __restrict__ edst,
                                                      const float* __restrict__ eval,
                                                      int* __restrict__ bcur,
                                                      int2* __restrict__ binned) {
    __shared__ char smem[22656];                   // GEMM 16.1KB / coarse 22.1KB

    const int tid  = threadIdx.x;
    const int lane = tid & 63;
    const int wv   = tid >> 6;
    const int bid  = blockIdx.x;

    const bool is_coarse = ((bid % 5) == 4) || (bid == TOTAL_BLOCKS - 1);

    if (is_coarse) {
        // ---- coarse binning with in-LDS counting sort (2048-edge chunk) ----
        const int blk = (bid == TOTAL_BLOCKS - 1) ? (BIN_BLOCKS - 1) : (bid / 5);
        int*   cnt   = (int*)smem;                 // [196]
        int*   lbase = (int*)smem + 256;           // [196]
        int*   sbase = (int*)smem + 512;           // [196]
        int*   cur   = (int*)smem + 768;           // [196]
        int2*  lrec  = (int2*)(smem + 4096);       // [2048] 16 KB
        unsigned char* lbid = (unsigned char*)smem + 20480;  // [2048]

        const int cb  = blk * EPB;
        const int lim = (N_EDGES - cb < EPB) ? (N_EDGES - cb) : EPB;

        if (tid < NBUCK) cnt[tid] = 0;
        __syncthreads();
        for (int i = tid; i < lim; i += 256)
            atomicAdd(&cnt[edst[cb + i] >> BSHIFT], 1);
        __syncthreads();

        // exclusive scan of cnt[0..195] -> lbase
        {
            __shared__ int wsum[4];
            const int v = (tid < NBUCK) ? cnt[tid] : 0;
            int sv = v;
#pragma unroll
            for (int d = 1; d < 64; d <<= 1) {
                const int t = __shfl_up(sv, d, 64);
                if (lane >= d) sv += t;
            }
            if (lane == 63) wsum[wv] = sv;
            __syncthreads();
            int wx = 0;
#pragma unroll
            for (int w = 0; w < 4; ++w) if (w < wv) wx += wsum[w];
            if (tid < NBUCK) {
                const int ex = wx + sv - v;
                lbase[tid] = ex;
                cur[tid]   = ex;
                sbase[tid] = v ? atomicAdd(&bcur[tid * BSTRIDE], v) : 0;
            }
        }
        __syncthreads();

        // scatter into LDS in bucket-sorted order
        for (int i = tid; i < lim; i += 256) {
            const int d = edst[cb + i];
            const int b = d >> BSHIFT;
            const int pos = atomicAdd(&cur[b], 1);
            int2 rec;
            rec.x = esrc[cb + i] | ((d & 511) << 20);
            rec.y = __float_as_int(eval[cb + i]);
            lrec[pos] = rec;
            lbid[pos] = (unsigned char)b;
        }
        __syncthreads();

        // write out sorted: consecutive i -> consecutive global positions
        for (int i = tid; i < lim; i += 256) {
            const int b   = lbid[i];
            const int off = sbase[b] + (i - lbase[b]);
            if (off < BCAP)
                binned[(size_t)b * BCAP + off] = lrec[i];
        }
        return;
    }

    // ---- GEMM: 32 rows x 128 cols; 4 waves each own 32 rows x 32 cols ----
    const int gidx = bid - bid / 5;                // de-interleaved GEMM index
    ushort* xt = (ushort*)smem;
    const int row0 = gidx * GEMM_ROWS;             // exact: no bounds checks
    const int wid  = wv;                           // col quarter 0..3

    // stage: 8 iters, 4 rows/iter, convert f32->bf16, swizzled LDS store
#pragma unroll 4
    for (int it = 0; it < 8; ++it) {
        const int tr = it * 4 + (tid >> 6);
        const int tc = (tid & 63) * 4;
        const float4 v = *reinterpret_cast<const float4*>(
            X + (size_t)(row0 + tr) * IN_DIM + tc);
        ushort4 b4;
        b4.x = f2bf(v.x); b4.y = f2bf(v.y); b4.z = f2bf(v.z); b4.w = f2bf(v.w);
        const int byte = (tr * 512 + tc * 2) ^ ((tr & 7) << 4);
        *reinterpret_cast<ushort4*>((char*)xt + byte) = b4;
    }

    // preload ALL B fragments for this wave (16 x 16B = 64 VGPRs, L2-hot);
    // overlaps the X staging latency, removes per-kk L2 stalls.
    bf16x8 Bfr[8][2];
#pragma unroll
    for (int kk = 0; kk < 8; ++kk)
#pragma unroll
        for (int n = 0; n < 2; ++n)
            Bfr[kk][n] = Bp[(size_t)(kk * 8 + wid * 2 + n) * 64 + lane];

    __syncthreads();

    const int rlo  = lane & 15;
    const int kseg = lane >> 4;
    const int rl0  = rlo;                          // A-frag local rows
    const int rl1  = rlo + 16;
    const int rxor = (rlo & 7) << 4;

    f32x4 acc[2][2] = {};

#pragma unroll
    for (int kk = 0; kk < 8; ++kk) {
        const int cb2 = (kk * 64 + kseg * 16) ^ rxor;
        const bf16x8 A0 = *reinterpret_cast<const bf16x8*>((const char*)xt + rl0 * 512 + cb2);
        const bf16x8 A1 = *reinterpret_cast<const bf16x8*>((const char*)xt + rl1 * 512 + cb2);
#pragma unroll
        for (int n = 0; n < 2; ++n) {
            acc[0][n] = __builtin_amdgcn_mfma_f32_16x16x32_bf16(A0, Bfr[kk][n], acc[0][n], 0, 0, 0);
            acc[1][n] = __builtin_amdgcn_mfma_f32_16x16x32_bf16(A1, Bfr[kk][n], acc[1][n], 0, 0, 0);
        }
    }

    // C/D layout: col = wid*32 + n*16 + rlo, row = i*16 + kseg*4 + r
#pragma unroll
    for (int i = 0; i < 2; ++i)
#pragma unroll
        for (int r = 0; r < 4; ++r)
#pragma unroll
            for (int n = 0; n < 2; ++n)
                H[(size_t)(row0 + i * 16 + kseg * 4 + r) * OUT_DIM
                  + wid * 32 + n * 16 + rlo] = f2bf(acc[i][n][r]);
}

// ------- Fine pass (scan folded in): per-bucket node-hist -> offsets + CSR -
__global__ __launch_bounds__(1024) void bin_fine(const int* __restrict__ bcur,
                                                 const int2* __restrict__ binned,
                                                 int* __restrict__ offsets,
                                                 int2* __restrict__ recs) {
    __shared__ int nh[512];
    __shared__ int cur[512];
    __shared__ int ws[4];
    __shared__ int wsB[4];
    __shared__ int base_out_s;
    const int b   = blockIdx.x;
    const int tid = threadIdx.x, lane = tid & 63, wid = tid >> 6;
    const int node0 = b << BSHIFT;
    int nn = N_NODES - node0; if (nn > 512) nn = 512;
    int size = bcur[b * BSTRIDE]; if (size > BCAP) size = BCAP;
    const int2* in = binned + (size_t)b * BCAP;

    // per-block exclusive prefix over the 196 bucket sizes
    if (tid < 256) {
        const int v = (tid < NBUCK) ? bcur[tid * BSTRIDE] : 0;
        int sv = v;
#pragma unroll
        for (int d = 1; d < 64; d <<= 1) {
            const int t = __shfl_up(sv, d, 64);
            if (lane >= d) sv += t;
        }
        if (lane == 63) wsB[wid] = sv;
        __syncthreads();
        int wx = 0;
#pragma unroll
        for (int w = 0; w < 4; ++w) if (w < wid) wx += wsB[w];
        if (tid == b) base_out_s = wx + sv - v;    // exclusive prefix at b
    } else {
        __syncthreads();
    }

    if (tid < 512) nh[tid] = 0;
    __syncthreads();
    const int base_out = base_out_s;
    for (int k = tid; k < size; k += 1024)
        atomicAdd(&nh[(in[k].x >> 20) & 511], 1);
    __syncthreads();

    // exclusive scan over nh[0..511]; threads 0..255 own pair (2t, 2t+1)
    int a0 = 0, ts = 0, sv = 0;
    if (tid < 256) {
        a0 = nh[2 * tid];
        const int a1 = nh[2 * tid + 1];
        ts = a0 + a1;
        sv = ts;
#pragma unroll
        for (int d = 1; d < 64; d <<= 1) {
            const int t = __shfl_up(sv, d, 64);
            if (lane >= d) sv += t;
        }
        if (lane == 63) ws[wid] = sv;
    }
    __syncthreads();
    if (tid < 256) {
        int wx = 0;
#pragma unroll
        for (int w = 0; w < 4; ++w) if (w < wid) wx += ws[w];
        const int ex = wx + sv - ts;               // exclusive prefix of pair
        cur[2 * tid]     = base_out + ex;
        cur[2 * tid + 1] = base_out + ex + a0;
        if (2 * tid < nn)     offsets[node0 + 2 * tid]     = base_out + ex;
        if (2 * tid + 1 < nn) offsets[node0 + 2 * tid + 1] = base_out + ex + a0;
    }
    if (b == 0 && tid == 0) offsets[N_NODES] = N_EDGES;
    __syncthreads();

    for (int k = tid; k < size; k += 1024) {
        const int2 r = in[k];
        const int pos = atomicAdd(&cur[(r.x >> 20) & 511], 1);
        int2 o; o.x = r.x & 0xFFFFF; o.y = r.y;
        recs[pos] = o;
    }
}

// ------- SpMM pull: 4 nodes/wave, 16 lanes/node, 8-edge unroll, ReLU -------
__global__ __launch_bounds__(256) void spmm_pull(const ushort* __restrict__ H,
                                                 const int* __restrict__ offsets,
                                                 const int2* __restrict__ recs,
                                                 float* __restrict__ out) {
    const int tid   = threadIdx.x;
    const int lane  = tid & 63;
    const int g     = lane >> 4;                   // node group 0..3
    const int c     = lane & 15;                   // 16B col-chunk 0..15
    const int gwave = blockIdx.x * 4 + (tid >> 6);
    const int node  = gwave * 4 + g;
    if (node >= N_NODES) return;

    const int beg = offsets[node];
    const int end = offsets[node + 1];

    float a0 = 0.f, a1 = 0.f, a2 = 0.f, a3 = 0.f;
    float a4 = 0.f, a5 = 0.f, a6 = 0.f, a7 = 0.f;

#define ACC(h, v)  {                                                      \
        a0 = fmaf(v, bflo(h.x), a0);  a1 = fmaf(v, bfhi(h.x), a1);        \
        a2 = fmaf(v, bflo(h.y), a2);  a3 = fmaf(v, bfhi(h.y), a3);        \
        a4 = fmaf(v, bflo(h.z), a4);  a5 = fmaf(v, bfhi(h.z), a5);        \
        a6 = fmaf(v, bflo(h.w), a6);  a7 = fmaf(v, bfhi(h.w), a7); }

    int e = beg;
    for (; e + 7 < end; e += 8) {                  // 8-edge unroll: 8 gathers in flight
        const int2 r0 = recs[e + 0], r1 = recs[e + 1];
        const int2 r2 = recs[e + 2], r3 = recs[e + 3];
        const int2 r4 = recs[e + 4], r5 = recs[e + 5];
        const int2 r6 = recs[e + 6], r7 = recs[e + 7];
        const uint4 h0 = *((const uint4*)(H + (size_t)r0.x * OUT_DIM) + c);
        const uint4 h1 = *((const uint4*)(H + (size_t)r1.x * OUT_DIM) + c);
        const uint4 h2 = *((const uint4*)(H + (size_t)r2.x * OUT_DIM) + c);
        const uint4 h3 = *((const uint4*)(H + (size_t)r3.x * OUT_DIM) + c);
        const uint4 h4 = *((const uint4*)(H + (size_t)r4.x * OUT_DIM) + c);
        const uint4 h5 = *((const uint4*)(H + (size_t)r5.x * OUT_DIM) + c);
        const uint4 h6 = *((const uint4*)(H + (size_t)r6.x * OUT_DIM) + c);
        const uint4 h7 = *((const uint4*)(H + (size_t)r7.x * OUT_DIM) + c);
        ACC(h0, __int_as_float(r0.y));  ACC(h1, __int_as_float(r1.y));
        ACC(h2, __int_as_float(r2.y));  ACC(h3, __int_as_float(r3.y));
        ACC(h4, __int_as_float(r4.y));  ACC(h5, __int_as_float(r5.y));
        ACC(h6, __int_as_float(r6.y));  ACC(h7, __int_as_float(r7.y));
    }
    for (; e + 1 < end; e += 2) {
        const int2 r0 = recs[e + 0], r1 = recs[e + 1];
        const uint4 h0 = *((const uint4*)(H + (size_t)r0.x * OUT_DIM) + c);
        const uint4 h1 = *((const uint4*)(H + (size_t)r1.x * OUT_DIM) + c);
        ACC(h0, __int_as_float(r0.y));  ACC(h1, __int_as_float(r1.y));
    }
    if (e < end) {
        const int2 r0 = recs[e];
        const uint4 h0 = *((const uint4*)(H + (size_t)r0.x * OUT_DIM) + c);
        ACC(h0, __int_as_float(r0.y));
    }
#undef ACC

    float* op = out + (size_t)node * OUT_DIM + c * 8;
    float4 o0, o1;
    o0.x = fmaxf(a0, 0.f); o0.y = fmaxf(a1, 0.f);
    o0.z = fmaxf(a2, 0.f); o0.w = fmaxf(a3, 0.f);
    o1.x = fmaxf(a4, 0.f); o1.y = fmaxf(a5, 0.f);
    o1.z = fmaxf(a6, 0.f); o1.w = fmaxf(a7, 0.f);
    *reinterpret_cast<float4*>(op)     = o0;
    *reinterpret_cast<float4*>(op + 4) = o1;
}

extern "C" void kernel_launch(void* const* d_in, const int* in_sizes, int n_in,
                              void* d_out, int out_size, void* d_ws, size_t ws_size,
                              hipStream_t stream) {
    const float* X    = (const float*)d_in[0];   // [N_NODES, IN_DIM]
    const float* W    = (const float*)d_in[1];   // [IN_DIM, OUT_DIM]
    const int*   esrc = (const int*)d_in[2];     // [N_EDGES]
    const int*   edst = (const int*)d_in[3];     // [N_EDGES]
    const float* eval = (const float*)d_in[4];   // [N_EDGES]
    float*       out  = (float*)d_out;           // [N_NODES, OUT_DIM]

    // Workspace layout (~55.4 MB)
    char* ws = (char*)d_ws;
    ushort* Hb     = (ushort*)ws;  ws += (size_t)N_NODES * OUT_DIM * sizeof(ushort);   // 25.6 MB
    ushort* Wp     = (ushort*)ws;  ws += (size_t)4096 * 8 * sizeof(ushort);            // 64 KB
    int*    offsets= (int*)ws;     ws += (((size_t)(N_NODES + 1) * 4 + 127) & ~(size_t)127);
    int*    bcur   = (int*)ws;     ws += (size_t)NBUCK * BSTRIDE * 4;                  // 12.5 KB padded
    int2*   binned = (int2*)ws;    ws += (size_t)NBUCK * BCAP * sizeof(int2);          // 16.1 MB
    int2*   recs   = (int2*)ws;    // 12.8 MB

    // 1) Pack W (+ zero bucket cursors); interleaved [GEMM || sorted coarse]
    pack_w<<<16, 256, 0, stream>>>(W, Wp, bcur);
    gemm_coarse<<<TOTAL_BLOCKS, 256, 0, stream>>>(X, (const bf16x8*)Wp, Hb,
                                                  esrc, edst, eval, bcur, binned);

    // 2) Per-bucket CSR finalize (bucket-base scan folded in)
    bin_fine<<<NBUCK, 1024, 0, stream>>>(bcur, binned, offsets, recs);

    // 3) Pull-SpMM + ReLU: 4 nodes per wave, 16 lanes each
    spmm_pull<<<(N_NODES + 15) / 16, 256, 0, stream>>>(Hb, offsets, recs, out);
}